// Round 3
// baseline (110.137 us; speedup 1.0000x reference)
//
#include <hip/hip_runtime.h>

// MoE experts: route -> gather(bf16) -> grouped GEMM1+silu -> grouped GEMM2 -> atomic combine
#define E_ 16
#define T_ 2048
#define H_ 1024
#define I_ 512
#define NPAIR 4096             // T*K token-expert pairs

typedef __bf16 bf16x8 __attribute__((ext_vector_type(8)));
typedef float  f32x4  __attribute__((ext_vector_type(4)));

static __device__ __forceinline__ unsigned short f2bf(float f) {
    __bf16 h = (__bf16)f;                       // RNE
    return __builtin_bit_cast(unsigned short, h);
}

static __device__ __forceinline__ uint4 pack8(const float* v) {
    union { unsigned short us[8]; uint4 u; } r;
    #pragma unroll
    for (int i = 0; i < 8; ++i) r.us[i] = f2bf(v[i]);
    return r.u;
}

// async global->LDS, 16B per lane; dest is wave-uniform base + lane*16 (linear)
static __device__ __forceinline__ void gl_lds16(const void* g, void* l) {
    __builtin_amdgcn_global_load_lds(
        (const __attribute__((address_space(1))) unsigned int*)g,
        (__attribute__((address_space(3))) unsigned int*)l,
        16, 0, 0);
}

// ---------------- routing: stable counting sort of 4096 pairs by expert ----
__global__ __launch_bounds__(256) void route_kernel(
    const float* __restrict__ tw, const int* __restrict__ ti,
    int* __restrict__ offs, int* __restrict__ pair_ts, float* __restrict__ pair_w)
{
    __shared__ unsigned short hist[256][E_];
    __shared__ int ebase[E_];
    const int tid = threadIdx.x;

    int e_loc[16];
    unsigned short h[E_];
    for (int e = 0; e < E_; ++e) h[e] = 0;
    for (int i = 0; i < 16; ++i) {
        int p = tid * 16 + i;
        int e = ti[p];
        e_loc[i] = e;
        h[e]++;
    }
    for (int e = 0; e < E_; ++e) hist[tid][e] = h[e];
    __syncthreads();

    if (tid < E_) {
        int e = tid, run = 0;
        for (int t = 0; t < 256; ++t) {
            unsigned short c = hist[t][e];
            hist[t][e] = (unsigned short)run;
            run += c;
        }
        ebase[e] = run;
    }
    __syncthreads();
    if (tid == 0) {
        int run = 0;
        for (int e = 0; e < E_; ++e) { int c = ebase[e]; offs[e] = run; ebase[e] = run; run += c; }
        offs[E_] = run;
    }
    __syncthreads();

    int cur[E_];
    for (int e = 0; e < E_; ++e) cur[e] = ebase[e] + hist[tid][e];
    for (int i = 0; i < 16; ++i) {
        int p = tid * 16 + i;
        int e = e_loc[i];
        int pos = cur[e]++;
        pair_ts[pos] = p;          // t = p>>1
        pair_w[pos]  = tw[p];
    }
}

// ---------------- gather: Ag[q][:] = bf16(X[token(q)][:]) ------------------
__global__ __launch_bounds__(256) void gather_kernel(
    const float* __restrict__ X, const int* __restrict__ pair_ts,
    unsigned short* __restrict__ Ag)
{
    const int q = blockIdx.x;
    const int t = pair_ts[q] >> 1;
    const int c = threadIdx.x * 4;
    const float4 x = *(const float4*)&X[(size_t)t * H_ + c];
    ushort4 b; b.x = f2bf(x.x); b.y = f2bf(x.y); b.z = f2bf(x.z); b.w = f2bf(x.w);
    *(ushort4*)&Ag[(size_t)q * H_ + c] = b;
}

// ---------------- grouped GEMM1 + fused silu-gate --------------------------
// BM=256, BN=64 (32 gate + 32 up interleaved per wave), BK=64, 512 thr (8 waves, 64x32/wave).
// LDS double-buffered; A via global_load_lds (pre-swizzled source), B reg-staged+converted.
// XOR swizzle: LDS[row][granule g] holds SRC[row][g ^ (row&7)] (16B granules).
__global__ __launch_bounds__(512) void gemm1_kernel(
    const unsigned short* __restrict__ Ag, const float* __restrict__ W1,
    const int* __restrict__ offs, unsigned short* __restrict__ act)
{
    const int e    = blockIdx.z;
    const int rbeg = offs[e], rend = offs[e + 1];
    const int ne   = rend - rbeg;
    const int row0 = blockIdx.y * 256;
    if (row0 >= ne) return;
    const int c0 = blockIdx.x * 32;          // gate col block; up = I_ + same

    __shared__ unsigned short As[2][256][64];   // 64 KB
    __shared__ unsigned short Bs[2][64][64];    // 16 KB

    const int tid  = threadIdx.x;
    const int lane = tid & 63;
    const int w    = tid >> 6;        // 0..7
    const int wm   = w >> 1;          // 0..3
    const int wn   = w & 1;           // 0..1
    const int lrow = lane & 15;
    const int lk   = lane >> 4;

    const float* __restrict__ W1e = W1 + (size_t)e * (H_ * 2 * I_);

    // A staging: wave w stages rows [w*32, w*32+32) as 4 chunks of 8 rows.
    const int r8 = lane >> 3, gr = lane & 7;
    const unsigned short* asrc[4];
    for (int i = 0; i < 4; ++i) {
        int rl = w * 32 + i * 8 + r8;
        int q  = rbeg + row0 + rl;
        if (q > rend - 1) q = rend - 1;
        asrc[i] = Ag + (size_t)q * H_ + ((gr ^ r8) * 8);   // pre-swizzled source granule
    }

    // B staging: thread -> Bs row bn=lane, k-slice w*8..w*8+8.
    // Bs row bn maps to global col: half=(bn>>4)&1 (0 gate,1 up), grp=bn>>5, sub=bn&15
    const int bn    = lane;
    const int bcol  = ((bn >> 4) & 1) * I_ + c0 + (bn >> 5) * 16 + (bn & 15);
    const int bwoff = ((w ^ (bn & 7)) * 8);    // swizzled granule for LDS write
    const float* __restrict__ bsrc = W1e + (size_t)(w * 8) * (2 * I_) + bcol;

    f32x4 acc[4][2];
    for (int m = 0; m < 4; ++m)
        for (int n = 0; n < 2; ++n)
            acc[m][n] = f32x4{0.f, 0.f, 0.f, 0.f};

    // prologue: stage kt=0 into buf 0
    #pragma unroll
    for (int i = 0; i < 4; ++i) gl_lds16(asrc[i], &As[0][w * 32 + i * 8][0]);
    {
        float bv[8];
        #pragma unroll
        for (int i = 0; i < 8; ++i) bv[i] = bsrc[(size_t)i * (2 * I_)];
        *(uint4*)&Bs[0][bn][bwoff] = pack8(bv);
    }
    __syncthreads();

    int cur = 0;
    for (int kt = 0; kt < H_ / 64; ++kt) {
        const int nxt = cur ^ 1;
        const bool more = (kt + 1) < H_ / 64;
        float bv[8];
        if (more) {
            const int kb = (kt + 1) * 64;
            #pragma unroll
            for (int i = 0; i < 4; ++i) gl_lds16(asrc[i] + kb, &As[nxt][w * 32 + i * 8][0]);
            #pragma unroll
            for (int i = 0; i < 8; ++i) bv[i] = bsrc[(size_t)(kb + i) * (2 * I_)];
        }
        #pragma unroll
        for (int kk = 0; kk < 64; kk += 32) {
            const int j0 = kk >> 3;
            bf16x8 af[4], bfr[2];
            #pragma unroll
            for (int m = 0; m < 4; ++m) {
                int row = wm * 64 + m * 16 + lrow;
                af[m] = *(const bf16x8*)&As[cur][row][((j0 + lk) ^ (row & 7)) * 8];
            }
            #pragma unroll
            for (int n = 0; n < 2; ++n) {
                int col = wn * 32 + n * 16 + lrow;
                bfr[n] = *(const bf16x8*)&Bs[cur][col][((j0 + lk) ^ (col & 7)) * 8];
            }
            #pragma unroll
            for (int m = 0; m < 4; ++m)
                #pragma unroll
                for (int n = 0; n < 2; ++n)
                    acc[m][n] = __builtin_amdgcn_mfma_f32_16x16x32_bf16(af[m], bfr[n], acc[m][n], 0, 0, 0);
        }
        if (more) *(uint4*)&Bs[nxt][bn][bwoff] = pack8(bv);
        __syncthreads();
        cur = nxt;
    }

    // epilogue: lane holds gate (frag 0) and up (frag 1) for same (row, col)
    for (int m = 0; m < 4; ++m) {
        #pragma unroll
        for (int reg = 0; reg < 4; ++reg) {
            int rloc = wm * 64 + m * 16 + lk * 4 + reg;
            if (row0 + rloc < ne) {
                int q = rbeg + row0 + rloc;
                float g = acc[m][0][reg], u = acc[m][1][reg];
                float a = g / (1.f + __expf(-g)) * u;
                act[(size_t)q * I_ + c0 + wn * 16 + lrow] = f2bf(a);
            }
        }
    }
}

// ---------------- grouped GEMM2 + weighted atomic combine ------------------
// BM=256, BN=64, BK=64 over K=I_=512; same pipeline as gemm1.
__global__ __launch_bounds__(512) void gemm2_kernel(
    const unsigned short* __restrict__ act, const float* __restrict__ W2,
    const int* __restrict__ offs, const int* __restrict__ pair_ts,
    const float* __restrict__ pair_w, float* __restrict__ out)
{
    const int e    = blockIdx.z;
    const int rbeg = offs[e], rend = offs[e + 1];
    const int ne   = rend - rbeg;
    const int row0 = blockIdx.y * 256;
    if (row0 >= ne) return;
    const int c0 = blockIdx.x * 64;

    __shared__ unsigned short As[2][256][64];
    __shared__ unsigned short Bs[2][64][64];

    const int tid  = threadIdx.x;
    const int lane = tid & 63;
    const int w    = tid >> 6;
    const int wm   = w >> 1;
    const int wn   = w & 1;
    const int lrow = lane & 15;
    const int lk   = lane >> 4;

    const float* __restrict__ W2e = W2 + (size_t)e * (I_ * H_);

    const int r8 = lane >> 3, gr = lane & 7;
    const unsigned short* asrc[4];
    for (int i = 0; i < 4; ++i) {
        int rl = w * 32 + i * 8 + r8;
        int q  = rbeg + row0 + rl;
        if (q > rend - 1) q = rend - 1;
        asrc[i] = act + (size_t)q * I_ + ((gr ^ r8) * 8);
    }

    const int bn    = lane;
    const int bwoff = ((w ^ (bn & 7)) * 8);
    const float* __restrict__ bsrc = W2e + (size_t)(w * 8) * H_ + c0 + bn;

    f32x4 acc[4][2];
    for (int m = 0; m < 4; ++m)
        for (int n = 0; n < 2; ++n)
            acc[m][n] = f32x4{0.f, 0.f, 0.f, 0.f};

    #pragma unroll
    for (int i = 0; i < 4; ++i) gl_lds16(asrc[i], &As[0][w * 32 + i * 8][0]);
    {
        float bv[8];
        #pragma unroll
        for (int i = 0; i < 8; ++i) bv[i] = bsrc[(size_t)i * H_];
        *(uint4*)&Bs[0][bn][bwoff] = pack8(bv);
    }
    __syncthreads();

    int cur = 0;
    for (int kt = 0; kt < I_ / 64; ++kt) {
        const int nxt = cur ^ 1;
        const bool more = (kt + 1) < I_ / 64;
        float bv[8];
        if (more) {
            const int kb = (kt + 1) * 64;
            #pragma unroll
            for (int i = 0; i < 4; ++i) gl_lds16(asrc[i] + kb, &As[nxt][w * 32 + i * 8][0]);
            #pragma unroll
            for (int i = 0; i < 8; ++i) bv[i] = bsrc[(size_t)(kb + i) * H_];
        }
        #pragma unroll
        for (int kk = 0; kk < 64; kk += 32) {
            const int j0 = kk >> 3;
            bf16x8 af[4], bfr[2];
            #pragma unroll
            for (int m = 0; m < 4; ++m) {
                int row = wm * 64 + m * 16 + lrow;
                af[m] = *(const bf16x8*)&As[cur][row][((j0 + lk) ^ (row & 7)) * 8];
            }
            #pragma unroll
            for (int n = 0; n < 2; ++n) {
                int col = wn * 32 + n * 16 + lrow;
                bfr[n] = *(const bf16x8*)&Bs[cur][col][((j0 + lk) ^ (col & 7)) * 8];
            }
            #pragma unroll
            for (int m = 0; m < 4; ++m)
                #pragma unroll
                for (int n = 0; n < 2; ++n)
                    acc[m][n] = __builtin_amdgcn_mfma_f32_16x16x32_bf16(af[m], bfr[n], acc[m][n], 0, 0, 0);
        }
        if (more) *(uint4*)&Bs[nxt][bn][bwoff] = pack8(bv);
        __syncthreads();
        cur = nxt;
    }

    for (int m = 0; m < 4; ++m) {
        #pragma unroll
        for (int reg = 0; reg < 4; ++reg) {
            int rloc = wm * 64 + m * 16 + lk * 4 + reg;
            if (row0 + rloc < ne) {
                int q   = rbeg + row0 + rloc;
                int t   = pair_ts[q] >> 1;
                float wt = pair_w[q];
                #pragma unroll
                for (int n = 0; n < 2; ++n) {
                    int cg = c0 + wn * 32 + n * 16 + lrow;
                    atomicAdd(&out[(size_t)t * H_ + cg], wt * acc[m][n][reg]);
                }
            }
        }
    }
}

extern "C" void kernel_launch(void* const* d_in, const int* in_sizes, int n_in,
                              void* d_out, int out_size, void* d_ws, size_t ws_size,
                              hipStream_t stream)
{
    const float* X  = (const float*)d_in[0];   // [T,H]
    const float* tw = (const float*)d_in[1];   // [T,K]
    const int*   ti = (const int*)d_in[2];     // [T,K]
    const float* W1 = (const float*)d_in[3];   // [E,H,2I]
    const float* W2 = (const float*)d_in[4];   // [E,I,H]
    float* out = (float*)d_out;                // [T,H] fp32

    char* ws = (char*)d_ws;
    int*   offs    = (int*)(ws);
    int*   pair_ts = (int*)(ws + 256);
    float* pair_w  = (float*)(ws + 256 + NPAIR * 4);
    unsigned short* Ag  = (unsigned short*)(ws + (1u << 16));                          // 8 MiB
    unsigned short* act = (unsigned short*)(ws + (1u << 16) + (size_t)NPAIR * H_ * 2); // 4 MiB

    hipMemsetAsync(d_out, 0, (size_t)out_size * sizeof(float), stream);

    route_kernel<<<1, 256, 0, stream>>>(tw, ti, offs, pair_ts, pair_w);

    gather_kernel<<<NPAIR, 256, 0, stream>>>(X, pair_ts, Ag);

    gemm1_kernel<<<dim3(I_ / 32, NPAIR / 256, E_), 512, 0, stream>>>(Ag, W1, offs, act);

    gemm2_kernel<<<dim3(H_ / 64, NPAIR / 256, E_), 512, 0, stream>>>(act, W2, offs, pair_ts, pair_w, out);
}

// Round 4
// 81.300 us; speedup vs baseline: 1.3547x; 1.3547x over previous
//
#include <hip/hip_runtime.h>

// MoE experts: route -> gather(bf16) -> grouped GEMM1+silu -> grouped GEMM2 -> atomic combine
#define E_ 16
#define T_ 2048
#define H_ 1024
#define I_ 512
#define NPAIR 4096             // T*K token-expert pairs

typedef __bf16 bf16x8 __attribute__((ext_vector_type(8)));
typedef float  f32x4  __attribute__((ext_vector_type(4)));

static __device__ __forceinline__ unsigned short f2bf(float f) {
    __bf16 h = (__bf16)f;                       // RNE
    return __builtin_bit_cast(unsigned short, h);
}

static __device__ __forceinline__ uint4 pack8(const float* v) {
    union { unsigned short us[8]; uint4 u; } r;
    #pragma unroll
    for (int i = 0; i < 8; ++i) r.us[i] = f2bf(v[i]);
    return r.u;
}

// async global->LDS, 16B/lane; dest wave-uniform base + lane*16 (linear)
static __device__ __forceinline__ void gl_lds16(const void* g, void* l) {
    __builtin_amdgcn_global_load_lds(
        (const __attribute__((address_space(1))) unsigned int*)g,
        (__attribute__((address_space(3))) unsigned int*)l,
        16, 0, 0);
}

// ---------------- routing: stable counting sort of 4096 pairs by expert ----
__global__ __launch_bounds__(256) void route_kernel(
    const float* __restrict__ tw, const int* __restrict__ ti,
    int* __restrict__ offs, int* __restrict__ pair_ts, float* __restrict__ pair_w)
{
    __shared__ unsigned short hist[256][E_];
    __shared__ int ebase[E_];
    const int tid = threadIdx.x;

    int e_loc[16];
    unsigned short h[E_];
    for (int e = 0; e < E_; ++e) h[e] = 0;
    for (int i = 0; i < 16; ++i) {
        int p = tid * 16 + i;
        int e = ti[p];
        e_loc[i] = e;
        h[e]++;
    }
    for (int e = 0; e < E_; ++e) hist[tid][e] = h[e];
    __syncthreads();

    if (tid < E_) {
        int e = tid, run = 0;
        for (int t = 0; t < 256; ++t) {
            unsigned short c = hist[t][e];
            hist[t][e] = (unsigned short)run;
            run += c;
        }
        ebase[e] = run;
    }
    __syncthreads();
    if (tid == 0) {
        int run = 0;
        for (int e = 0; e < E_; ++e) { int c = ebase[e]; offs[e] = run; ebase[e] = run; run += c; }
        offs[E_] = run;
    }
    __syncthreads();

    int cur[E_];
    for (int e = 0; e < E_; ++e) cur[e] = ebase[e] + hist[tid][e];
    for (int i = 0; i < 16; ++i) {
        int p = tid * 16 + i;
        int e = e_loc[i];
        int pos = cur[e]++;
        pair_ts[pos] = p;          // t = p>>1
        pair_w[pos]  = tw[p];
    }
}

// ---------------- gather: Ag[q][:] = bf16(X[token(q)][:]) ------------------
__global__ __launch_bounds__(256) void gather_kernel(
    const float* __restrict__ X, const int* __restrict__ pair_ts,
    unsigned short* __restrict__ Ag)
{
    const int q = blockIdx.x;
    const int t = pair_ts[q] >> 1;
    const int c = threadIdx.x * 4;
    const float4 x = *(const float4*)&X[(size_t)t * H_ + c];
    ushort4 b; b.x = f2bf(x.x); b.y = f2bf(x.y); b.z = f2bf(x.z); b.w = f2bf(x.w);
    *(ushort4*)&Ag[(size_t)q * H_ + c] = b;
}

// Shared MFMA micro-tile: 4 waves (2x2), wave tile 64x32, block 128x64, BK=64.
// XOR-swizzled LDS (16B granule g holds src granule g^(row&7)).
#define MFMA_TILE(AS, BS)                                                              \
    _Pragma("unroll")                                                                  \
    for (int kkj = 0; kkj < 2; ++kkj) {                                                \
        const int j0 = kkj * 4;                                                        \
        bf16x8 af[4], bfr[2];                                                          \
        _Pragma("unroll")                                                              \
        for (int m = 0; m < 4; ++m)                                                    \
            af[m] = *(const bf16x8*)&AS[wm * 64 + m * 16 + lrow][((j0 + lk) ^ (lrow & 7)) * 8]; \
        _Pragma("unroll")                                                              \
        for (int n = 0; n < 2; ++n)                                                    \
            bfr[n] = *(const bf16x8*)&BS[wn * 32 + n * 16 + lrow][((j0 + lk) ^ (lrow & 7)) * 8]; \
        _Pragma("unroll")                                                              \
        for (int m = 0; m < 4; ++m)                                                    \
            _Pragma("unroll")                                                          \
            for (int n = 0; n < 2; ++n)                                                \
                acc[m][n] = __builtin_amdgcn_mfma_f32_16x16x32_bf16(af[m], bfr[n], acc[m][n], 0, 0, 0); \
    }

// One pipelined K-step: issue all prefetch right after the previous barrier
// (drains at THIS step's barrier, covered by the MFMA burst). B data is loaded
// two steps ahead into registers, so the Bs write never waits.
#define PIPE_STEP(KT, NT, BSTRIDE, ASC, ASN, BSC, BSN, BVC, BVN)                       \
    {                                                                                  \
        if ((KT) + 1 < (NT)) {                                                         \
            const int kb_ = ((KT) + 1) * 64;                                           \
            _Pragma("unroll")                                                          \
            for (int i = 0; i < 4; ++i) gl_lds16(asrc[i] + kb_, &ASN[w * 32 + i * 8][0]); \
            *(uint4*)&BSN[bn][bg0] = pack8(&BVC[0]);                                   \
            *(uint4*)&BSN[bn][bg1] = pack8(&BVC[8]);                                   \
        }                                                                              \
        if ((KT) + 2 < (NT)) {                                                         \
            const int kb2_ = ((KT) + 2) * 64;                                          \
            _Pragma("unroll")                                                          \
            for (int i = 0; i < 16; ++i)                                               \
                BVN[i] = bsrc[(size_t)(kb2_ + w * 16 + i) * (BSTRIDE)];                \
        }                                                                              \
        MFMA_TILE(ASC, BSC)                                                            \
        __syncthreads();                                                               \
    }

// ---------------- grouped GEMM1 + fused silu-gate --------------------------
// BM=128, BN=64 (32 gate + 32 up), K=H_=1024 (16 steps).
__global__ __launch_bounds__(256) void gemm1_kernel(
    const unsigned short* __restrict__ Ag, const float* __restrict__ W1,
    const int* __restrict__ offs, unsigned short* __restrict__ act)
{
    const int e    = blockIdx.z;
    const int rbeg = offs[e], rend = offs[e + 1];
    const int ne   = rend - rbeg;
    const int row0 = blockIdx.y * 128;
    if (row0 >= ne) return;
    const int c0 = blockIdx.x * 32;          // act col block; gate cols c0.., up cols I_+c0..

    __shared__ unsigned short As0[128][64], As1[128][64];   // 16 KB each
    __shared__ unsigned short Bs0[64][64],  Bs1[64][64];    // 8 KB each

    const int tid  = threadIdx.x;
    const int lane = tid & 63;
    const int w    = tid >> 6;        // 0..3
    const int wm   = w >> 1, wn = w & 1;
    const int lrow = lane & 15;
    const int lk   = lane >> 4;

    const float* __restrict__ W1e = W1 + (size_t)e * (H_ * 2 * I_);

    // A staging: wave w stages rows [w*32, w*32+32), 8 rows per gl_lds16
    const int r8 = lane >> 3, gr = lane & 7;
    const unsigned short* asrc[4];
    #pragma unroll
    for (int i = 0; i < 4; ++i) {
        int q = rbeg + row0 + w * 32 + i * 8 + r8;
        if (q > rend - 1) q = rend - 1;
        asrc[i] = Ag + (size_t)q * H_ + (gr ^ r8) * 8;   // pre-swizzled source granule
    }

    // B staging: Bs rows wn*32+[0..15]=gate cols c0+wn*16+s, +[16..31]=up cols
    const int bn   = lane;
    const int bcol = ((bn >> 4) & 1) * I_ + c0 + (bn >> 5) * 16 + (bn & 15);
    const float* __restrict__ bsrc = W1e + bcol;
    const int bg0 = ((2 * w)     ^ (bn & 7)) * 8;
    const int bg1 = ((2 * w + 1) ^ (bn & 7)) * 8;

    f32x4 acc[4][2];
    #pragma unroll
    for (int m = 0; m < 4; ++m)
        #pragma unroll
        for (int n = 0; n < 2; ++n)
            acc[m][n] = f32x4{0.f, 0.f, 0.f, 0.f};

    // prologue: tile0 staged, tile1 B-data in regs
    float bv0[16], bv1[16];
    #pragma unroll
    for (int i = 0; i < 16; ++i) bv0[i] = bsrc[(size_t)(w * 16 + i) * (2 * I_)];
    #pragma unroll
    for (int i = 0; i < 16; ++i) bv1[i] = bsrc[(size_t)(64 + w * 16 + i) * (2 * I_)];
    #pragma unroll
    for (int i = 0; i < 4; ++i) gl_lds16(asrc[i], &As0[w * 32 + i * 8][0]);
    *(uint4*)&Bs0[bn][bg0] = pack8(&bv0[0]);
    *(uint4*)&Bs0[bn][bg1] = pack8(&bv0[8]);
    __syncthreads();

    for (int kt = 0; kt < 16; kt += 2) {
        PIPE_STEP(kt,     16, 2 * I_, As0, As1, Bs0, Bs1, bv1, bv0)
        PIPE_STEP(kt + 1, 16, 2 * I_, As1, As0, Bs1, Bs0, bv0, bv1)
    }

    // epilogue: frag 0 = gate, frag 1 = up for act col c0 + wn*16 + lrow
    for (int m = 0; m < 4; ++m) {
        #pragma unroll
        for (int reg = 0; reg < 4; ++reg) {
            int rloc = wm * 64 + m * 16 + lk * 4 + reg;
            if (row0 + rloc < ne) {
                int q = rbeg + row0 + rloc;
                float g = acc[m][0][reg], u = acc[m][1][reg];
                float a = g / (1.f + __expf(-g)) * u;
                act[(size_t)q * I_ + c0 + wn * 16 + lrow] = f2bf(a);
            }
        }
    }
}

// ---------------- grouped GEMM2 + weighted atomic combine ------------------
// BM=128, BN=64, K=I_=512 (8 steps).
__global__ __launch_bounds__(256) void gemm2_kernel(
    const unsigned short* __restrict__ act, const float* __restrict__ W2,
    const int* __restrict__ offs, const int* __restrict__ pair_ts,
    const float* __restrict__ pair_w, float* __restrict__ out)
{
    const int e    = blockIdx.z;
    const int rbeg = offs[e], rend = offs[e + 1];
    const int ne   = rend - rbeg;
    const int row0 = blockIdx.y * 128;
    if (row0 >= ne) return;
    const int c0 = blockIdx.x * 64;

    __shared__ unsigned short As0[128][64], As1[128][64];
    __shared__ unsigned short Bs0[64][64],  Bs1[64][64];

    const int tid  = threadIdx.x;
    const int lane = tid & 63;
    const int w    = tid >> 6;
    const int wm   = w >> 1, wn = w & 1;
    const int lrow = lane & 15;
    const int lk   = lane >> 4;

    const float* __restrict__ W2e = W2 + (size_t)e * (I_ * H_);

    const int r8 = lane >> 3, gr = lane & 7;
    const unsigned short* asrc[4];
    #pragma unroll
    for (int i = 0; i < 4; ++i) {
        int q = rbeg + row0 + w * 32 + i * 8 + r8;
        if (q > rend - 1) q = rend - 1;
        asrc[i] = act + (size_t)q * I_ + (gr ^ r8) * 8;
    }

    const int bn = lane;
    const float* __restrict__ bsrc = W2e + c0 + bn;
    const int bg0 = ((2 * w)     ^ (bn & 7)) * 8;
    const int bg1 = ((2 * w + 1) ^ (bn & 7)) * 8;

    f32x4 acc[4][2];
    #pragma unroll
    for (int m = 0; m < 4; ++m)
        #pragma unroll
        for (int n = 0; n < 2; ++n)
            acc[m][n] = f32x4{0.f, 0.f, 0.f, 0.f};

    float bv0[16], bv1[16];
    #pragma unroll
    for (int i = 0; i < 16; ++i) bv0[i] = bsrc[(size_t)(w * 16 + i) * H_];
    #pragma unroll
    for (int i = 0; i < 16; ++i) bv1[i] = bsrc[(size_t)(64 + w * 16 + i) * H_];
    #pragma unroll
    for (int i = 0; i < 4; ++i) gl_lds16(asrc[i], &As0[w * 32 + i * 8][0]);
    *(uint4*)&Bs0[bn][bg0] = pack8(&bv0[0]);
    *(uint4*)&Bs0[bn][bg1] = pack8(&bv0[8]);
    __syncthreads();

    for (int kt = 0; kt < 8; kt += 2) {
        PIPE_STEP(kt,     8, H_, As0, As1, Bs0, Bs1, bv1, bv0)
        PIPE_STEP(kt + 1, 8, H_, As1, As0, Bs1, Bs0, bv0, bv1)
    }

    for (int m = 0; m < 4; ++m) {
        #pragma unroll
        for (int reg = 0; reg < 4; ++reg) {
            int rloc = wm * 64 + m * 16 + lk * 4 + reg;
            if (row0 + rloc < ne) {
                int q   = rbeg + row0 + rloc;
                int t   = pair_ts[q] >> 1;
                float wt = pair_w[q];
                #pragma unroll
                for (int n = 0; n < 2; ++n) {
                    int cg = c0 + wn * 32 + n * 16 + lrow;
                    atomicAdd(&out[(size_t)t * H_ + cg], wt * acc[m][n][reg]);
                }
            }
        }
    }
}

extern "C" void kernel_launch(void* const* d_in, const int* in_sizes, int n_in,
                              void* d_out, int out_size, void* d_ws, size_t ws_size,
                              hipStream_t stream)
{
    const float* X  = (const float*)d_in[0];   // [T,H]
    const float* tw = (const float*)d_in[1];   // [T,K]
    const int*   ti = (const int*)d_in[2];     // [T,K]
    const float* W1 = (const float*)d_in[3];   // [E,H,2I]
    const float* W2 = (const float*)d_in[4];   // [E,I,H]
    float* out = (float*)d_out;                // [T,H] fp32

    char* ws = (char*)d_ws;
    int*   offs    = (int*)(ws);
    int*   pair_ts = (int*)(ws + 256);
    float* pair_w  = (float*)(ws + 256 + NPAIR * 4);
    unsigned short* Ag  = (unsigned short*)(ws + (1u << 16));                          // 8 MiB
    unsigned short* act = (unsigned short*)(ws + (1u << 16) + (size_t)NPAIR * H_ * 2); // 4 MiB

    hipMemsetAsync(d_out, 0, (size_t)out_size * sizeof(float), stream);

    route_kernel<<<1, 256, 0, stream>>>(tw, ti, offs, pair_ts, pair_w);

    gather_kernel<<<NPAIR, 256, 0, stream>>>(X, pair_ts, Ag);

    gemm1_kernel<<<dim3(I_ / 32, NPAIR / 128, E_), 256, 0, stream>>>(Ag, W1, offs, act);

    gemm2_kernel<<<dim3(H_ / 64, NPAIR / 128, E_), 256, 0, stream>>>(act, W2, offs, pair_ts, pair_w, out);
}

// Round 5
// 80.214 us; speedup vs baseline: 1.3731x; 1.0135x over previous
//
#include <hip/hip_runtime.h>

// MoE experts: route -> gather(bf16) -> grouped GEMM1+silu -> grouped GEMM2 -> atomic combine
#define E_ 16
#define T_ 2048
#define H_ 1024
#define I_ 512
#define NPAIR 4096             // T*K token-expert pairs
#define BM 128
#define MAXTILE 48             // sum ceil(ne/BM) <= 32 + 16

typedef __bf16 bf16x8 __attribute__((ext_vector_type(8)));
typedef float  f32x4  __attribute__((ext_vector_type(4)));

static __device__ __forceinline__ unsigned short f2bf(float f) {
    __bf16 h = (__bf16)f;                       // RNE
    return __builtin_bit_cast(unsigned short, h);
}

static __device__ __forceinline__ uint4 pack8(const float* v) {
    union { unsigned short us[8]; uint4 u; } r;
    #pragma unroll
    for (int i = 0; i < 8; ++i) r.us[i] = f2bf(v[i]);
    return r.u;
}

// async global->LDS, 16B/lane; dest wave-uniform base + lane*16 (linear)
static __device__ __forceinline__ void gl_lds16(const void* g, void* l) {
    __builtin_amdgcn_global_load_lds(
        (const __attribute__((address_space(1))) unsigned int*)g,
        (__attribute__((address_space(3))) unsigned int*)l,
        16, 0, 0);
}

// ---------------- routing: stable counting sort + tile map -----------------
__global__ __launch_bounds__(256) void route_kernel(
    const float* __restrict__ tw, const int* __restrict__ ti,
    int* __restrict__ offs, int* __restrict__ tile_e, int* __restrict__ tile_r,
    int* __restrict__ pair_ts, float* __restrict__ pair_w)
{
    __shared__ unsigned short hist[256][E_];
    __shared__ int ebase[E_];
    const int tid = threadIdx.x;

    int e_loc[16];
    unsigned short h[E_];
    for (int e = 0; e < E_; ++e) h[e] = 0;
    for (int i = 0; i < 16; ++i) {
        int p = tid * 16 + i;
        int e = ti[p];
        e_loc[i] = e;
        h[e]++;
    }
    for (int e = 0; e < E_; ++e) hist[tid][e] = h[e];
    __syncthreads();

    if (tid < E_) {
        int e = tid, run = 0;
        for (int t = 0; t < 256; ++t) {
            unsigned short c = hist[t][e];
            hist[t][e] = (unsigned short)run;
            run += c;
        }
        ebase[e] = run;
    }
    __syncthreads();
    if (tid == 0) {
        int run = 0, nt = 0;
        for (int e = 0; e < E_; ++e) {
            int c = ebase[e];
            offs[e] = run; ebase[e] = run;
            for (int r = 0; r < c; r += BM) { tile_e[nt] = e; tile_r[nt] = r; ++nt; }
            run += c;
        }
        offs[E_] = run;
        for (; nt < MAXTILE; ++nt) tile_e[nt] = -1;
    }
    __syncthreads();

    int cur[E_];
    for (int e = 0; e < E_; ++e) cur[e] = ebase[e] + hist[tid][e];
    for (int i = 0; i < 16; ++i) {
        int p = tid * 16 + i;
        int e = e_loc[i];
        int pos = cur[e]++;
        pair_ts[pos] = p;          // t = p>>1
        pair_w[pos]  = tw[p];
    }
}

// ---------------- gather: Ag[q][:] = bf16(X[token(q)][:]) ------------------
__global__ __launch_bounds__(256) void gather_kernel(
    const float* __restrict__ X, const int* __restrict__ pair_ts,
    unsigned short* __restrict__ Ag)
{
    const int q = blockIdx.x;
    const int t = pair_ts[q] >> 1;
    const int c = threadIdx.x * 4;
    const float4 x = *(const float4*)&X[(size_t)t * H_ + c];
    ushort4 b; b.x = f2bf(x.x); b.y = f2bf(x.y); b.z = f2bf(x.z); b.w = f2bf(x.w);
    *(ushort4*)&Ag[(size_t)q * H_ + c] = b;
}

// Shared MFMA micro-tile: 4 waves (2x2), wave tile 64x32, block 128x64, BK=64.
// XOR-swizzled LDS (16B granule g holds src granule g^(row&7)).
#define MFMA_TILE(AS, BS)                                                              \
    _Pragma("unroll")                                                                  \
    for (int kkj = 0; kkj < 2; ++kkj) {                                                \
        const int j0 = kkj * 4;                                                        \
        bf16x8 af[4], bfr[2];                                                          \
        _Pragma("unroll")                                                              \
        for (int m = 0; m < 4; ++m)                                                    \
            af[m] = *(const bf16x8*)&AS[wm * 64 + m * 16 + lrow][((j0 + lk) ^ (lrow & 7)) * 8]; \
        _Pragma("unroll")                                                              \
        for (int n = 0; n < 2; ++n)                                                    \
            bfr[n] = *(const bf16x8*)&BS[wn * 32 + n * 16 + lrow][((j0 + lk) ^ (lrow & 7)) * 8]; \
        _Pragma("unroll")                                                              \
        for (int m = 0; m < 4; ++m)                                                    \
            _Pragma("unroll")                                                          \
            for (int n = 0; n < 2; ++n)                                                \
                acc[m][n] = __builtin_amdgcn_mfma_f32_16x16x32_bf16(af[m], bfr[n], acc[m][n], 0, 0, 0); \
    }

// One pipelined K-step: issue all prefetch right after the previous barrier
// (drains at THIS step's barrier, covered by the MFMA burst). B data is loaded
// two steps ahead into registers, so the Bs write never waits.
#define PIPE_STEP(KT, NT, BSTRIDE, ASC, ASN, BSC, BSN, BVC, BVN)                       \
    {                                                                                  \
        if ((KT) + 1 < (NT)) {                                                         \
            const int kb_ = ((KT) + 1) * 64;                                           \
            _Pragma("unroll")                                                          \
            for (int i = 0; i < 4; ++i) gl_lds16(asrc[i] + kb_, &ASN[w * 32 + i * 8][0]); \
            *(uint4*)&BSN[bn][bg0] = pack8(&BVC[0]);                                   \
            *(uint4*)&BSN[bn][bg1] = pack8(&BVC[8]);                                   \
        }                                                                              \
        if ((KT) + 2 < (NT)) {                                                         \
            const int kb2_ = ((KT) + 2) * 64;                                          \
            _Pragma("unroll")                                                          \
            for (int i = 0; i < 16; ++i)                                               \
                BVN[i] = bsrc[(size_t)(kb2_ + w * 16 + i) * (BSTRIDE)];                \
        }                                                                              \
        MFMA_TILE(ASC, BSC)                                                            \
        __syncthreads();                                                               \
    }

// ---------------- grouped GEMM1 + fused silu-gate --------------------------
// BM=128, BN=64 (32 gate + 32 up), K=H_=1024 (16 steps). Dense tile-mapped grid.
__global__ __launch_bounds__(256, 3) void gemm1_kernel(
    const unsigned short* __restrict__ Ag, const float* __restrict__ W1,
    const int* __restrict__ offs, const int* __restrict__ tile_e,
    const int* __restrict__ tile_r, unsigned short* __restrict__ act)
{
    const int e = tile_e[blockIdx.y];
    if (e < 0) return;
    const int rbeg = offs[e], rend = offs[e + 1];
    const int ne   = rend - rbeg;
    const int row0 = tile_r[blockIdx.y];
    const int c0 = blockIdx.x * 32;          // act col block; gate cols c0.., up cols I_+c0..

    __shared__ unsigned short As0[128][64], As1[128][64];   // 16 KB each
    __shared__ unsigned short Bs0[64][64],  Bs1[64][64];    // 8 KB each

    const int tid  = threadIdx.x;
    const int lane = tid & 63;
    const int w    = tid >> 6;        // 0..3
    const int wm   = w >> 1, wn = w & 1;
    const int lrow = lane & 15;
    const int lk   = lane >> 4;

    const float* __restrict__ W1e = W1 + (size_t)e * (H_ * 2 * I_);

    // A staging: wave w stages rows [w*32, w*32+32), 8 rows per gl_lds16
    const int r8 = lane >> 3, gr = lane & 7;
    const unsigned short* asrc[4];
    #pragma unroll
    for (int i = 0; i < 4; ++i) {
        int q = rbeg + row0 + w * 32 + i * 8 + r8;
        if (q > rend - 1) q = rend - 1;
        asrc[i] = Ag + (size_t)q * H_ + (gr ^ r8) * 8;   // pre-swizzled source granule
    }

    // B staging: Bs rows wn*32+[0..15]=gate cols c0+wn*16+s, +[16..31]=up cols
    const int bn   = lane;
    const int bcol = ((bn >> 4) & 1) * I_ + c0 + (bn >> 5) * 16 + (bn & 15);
    const float* __restrict__ bsrc = W1e + bcol;
    const int bg0 = ((2 * w)     ^ (bn & 7)) * 8;
    const int bg1 = ((2 * w + 1) ^ (bn & 7)) * 8;

    f32x4 acc[4][2];
    #pragma unroll
    for (int m = 0; m < 4; ++m)
        #pragma unroll
        for (int n = 0; n < 2; ++n)
            acc[m][n] = f32x4{0.f, 0.f, 0.f, 0.f};

    // prologue: tile0 staged, tile1 B-data in regs
    float bv0[16], bv1[16];
    #pragma unroll
    for (int i = 0; i < 16; ++i) bv0[i] = bsrc[(size_t)(w * 16 + i) * (2 * I_)];
    #pragma unroll
    for (int i = 0; i < 16; ++i) bv1[i] = bsrc[(size_t)(64 + w * 16 + i) * (2 * I_)];
    #pragma unroll
    for (int i = 0; i < 4; ++i) gl_lds16(asrc[i], &As0[w * 32 + i * 8][0]);
    *(uint4*)&Bs0[bn][bg0] = pack8(&bv0[0]);
    *(uint4*)&Bs0[bn][bg1] = pack8(&bv0[8]);
    __syncthreads();

    for (int kt = 0; kt < 16; kt += 2) {
        PIPE_STEP(kt,     16, 2 * I_, As0, As1, Bs0, Bs1, bv1, bv0)
        PIPE_STEP(kt + 1, 16, 2 * I_, As1, As0, Bs1, Bs0, bv0, bv1)
    }

    // epilogue: frag 0 = gate, frag 1 = up for act col c0 + wn*16 + lrow
    for (int m = 0; m < 4; ++m) {
        #pragma unroll
        for (int reg = 0; reg < 4; ++reg) {
            int rloc = wm * 64 + m * 16 + lk * 4 + reg;
            if (row0 + rloc < ne) {
                int q = rbeg + row0 + rloc;
                float g = acc[m][0][reg], u = acc[m][1][reg];
                float a = g / (1.f + __expf(-g)) * u;
                act[(size_t)q * I_ + c0 + wn * 16 + lrow] = f2bf(a);
            }
        }
    }
}

// ---------------- grouped GEMM2 + weighted atomic combine ------------------
// BM=128, BN=64, K=I_=512 (8 steps). Dense tile-mapped grid.
__global__ __launch_bounds__(256, 3) void gemm2_kernel(
    const unsigned short* __restrict__ act, const float* __restrict__ W2,
    const int* __restrict__ offs, const int* __restrict__ tile_e,
    const int* __restrict__ tile_r, const int* __restrict__ pair_ts,
    const float* __restrict__ pair_w, float* __restrict__ out)
{
    const int e = tile_e[blockIdx.y];
    if (e < 0) return;
    const int rbeg = offs[e], rend = offs[e + 1];
    const int ne   = rend - rbeg;
    const int row0 = tile_r[blockIdx.y];
    const int c0 = blockIdx.x * 64;

    __shared__ unsigned short As0[128][64], As1[128][64];
    __shared__ unsigned short Bs0[64][64],  Bs1[64][64];

    const int tid  = threadIdx.x;
    const int lane = tid & 63;
    const int w    = tid >> 6;
    const int wm   = w >> 1, wn = w & 1;
    const int lrow = lane & 15;
    const int lk   = lane >> 4;

    const float* __restrict__ W2e = W2 + (size_t)e * (I_ * H_);

    const int r8 = lane >> 3, gr = lane & 7;
    const unsigned short* asrc[4];
    #pragma unroll
    for (int i = 0; i < 4; ++i) {
        int q = rbeg + row0 + w * 32 + i * 8 + r8;
        if (q > rend - 1) q = rend - 1;
        asrc[i] = act + (size_t)q * I_ + (gr ^ r8) * 8;
    }

    const int bn = lane;
    const float* __restrict__ bsrc = W2e + c0 + bn;
    const int bg0 = ((2 * w)     ^ (bn & 7)) * 8;
    const int bg1 = ((2 * w + 1) ^ (bn & 7)) * 8;

    f32x4 acc[4][2];
    #pragma unroll
    for (int m = 0; m < 4; ++m)
        #pragma unroll
        for (int n = 0; n < 2; ++n)
            acc[m][n] = f32x4{0.f, 0.f, 0.f, 0.f};

    float bv0[16], bv1[16];
    #pragma unroll
    for (int i = 0; i < 16; ++i) bv0[i] = bsrc[(size_t)(w * 16 + i) * H_];
    #pragma unroll
    for (int i = 0; i < 16; ++i) bv1[i] = bsrc[(size_t)(64 + w * 16 + i) * H_];
    #pragma unroll
    for (int i = 0; i < 4; ++i) gl_lds16(asrc[i], &As0[w * 32 + i * 8][0]);
    *(uint4*)&Bs0[bn][bg0] = pack8(&bv0[0]);
    *(uint4*)&Bs0[bn][bg1] = pack8(&bv0[8]);
    __syncthreads();

    for (int kt = 0; kt < 8; kt += 2) {
        PIPE_STEP(kt,     8, H_, As0, As1, Bs0, Bs1, bv1, bv0)
        PIPE_STEP(kt + 1, 8, H_, As1, As0, Bs1, Bs0, bv0, bv1)
    }

    for (int m = 0; m < 4; ++m) {
        #pragma unroll
        for (int reg = 0; reg < 4; ++reg) {
            int rloc = wm * 64 + m * 16 + lk * 4 + reg;
            if (row0 + rloc < ne) {
                int q   = rbeg + row0 + rloc;
                int t   = pair_ts[q] >> 1;
                float wt = pair_w[q];
                #pragma unroll
                for (int n = 0; n < 2; ++n) {
                    int cg = c0 + wn * 32 + n * 16 + lrow;
                    atomicAdd(&out[(size_t)t * H_ + cg], wt * acc[m][n][reg]);
                }
            }
        }
    }
}

extern "C" void kernel_launch(void* const* d_in, const int* in_sizes, int n_in,
                              void* d_out, int out_size, void* d_ws, size_t ws_size,
                              hipStream_t stream)
{
    const float* X  = (const float*)d_in[0];   // [T,H]
    const float* tw = (const float*)d_in[1];   // [T,K]
    const int*   ti = (const int*)d_in[2];     // [T,K]
    const float* W1 = (const float*)d_in[3];   // [E,H,2I]
    const float* W2 = (const float*)d_in[4];   // [E,I,H]
    float* out = (float*)d_out;                // [T,H] fp32

    char* ws = (char*)d_ws;
    int*   offs    = (int*)(ws);               // 17 ints
    int*   tile_e  = (int*)(ws + 128);         // MAXTILE ints
    int*   tile_r  = (int*)(ws + 128 + MAXTILE * 4);
    int*   pair_ts = (int*)(ws + 1024);
    float* pair_w  = (float*)(ws + 1024 + NPAIR * 4);
    unsigned short* Ag  = (unsigned short*)(ws + (1u << 16));                          // 8 MiB
    unsigned short* act = (unsigned short*)(ws + (1u << 16) + (size_t)NPAIR * H_ * 2); // 4 MiB

    hipMemsetAsync(d_out, 0, (size_t)out_size * sizeof(float), stream);

    route_kernel<<<1, 256, 0, stream>>>(tw, ti, offs, tile_e, tile_r, pair_ts, pair_w);

    gather_kernel<<<NPAIR, 256, 0, stream>>>(X, pair_ts, Ag);

    gemm1_kernel<<<dim3(I_ / 32, MAXTILE), 256, 0, stream>>>(Ag, W1, offs, tile_e, tile_r, act);

    gemm2_kernel<<<dim3(H_ / 64, MAXTILE), 256, 0, stream>>>(act, W2, offs, tile_e, tile_r, pair_ts, pair_w, out);
}